// Round 18
// baseline (137.979 us; speedup 1.0000x reference)
//
#include <hip/hip_runtime.h>

// Problem dims
#define BDIM 4
#define TDIM 2048
#define DDIM 2048
#define KLAM 4
#define CCH  64          // time chunks
#define TC   32          // TDIM / CCH

using short8 = __attribute__((ext_vector_type(8))) short;
using f32x4  = __attribute__((ext_vector_type(4))) float;
typedef unsigned short ushort_t;
typedef unsigned int   uint_t;

__device__ __forceinline__ uint_t f2bf(float f) {
  uint_t u = __builtin_bit_cast(uint_t, f);
  return (u + 0x7FFFu + ((u >> 16) & 1u)) >> 16;
}
__device__ __forceinline__ float bf2f(uint_t s) {
  uint_t u = s << 16;
  return __builtin_bit_cast(float, u);
}

#define NW8 ((DDIM * DDIM) / 8)          // 524288

// ---------------- fp32 -> bf16 convert (W only; x is read fp32 by gemm) ----
__global__ __launch_bounds__(256) void cvt_w(const float* __restrict__ in,
                                             uint4* __restrict__ out) {
  int i = blockIdx.x * 256 + threadIdx.x;
  const float4* in4 = (const float4*)in;
  float4 f0 = in4[2 * i];
  float4 f1 = in4[2 * i + 1];
  uint4 o;
  o.x = f2bf(f0.x) | (f2bf(f0.y) << 16);
  o.y = f2bf(f0.z) | (f2bf(f0.w) << 16);
  o.z = f2bf(f1.x) | (f2bf(f1.y) << 16);
  o.w = f2bf(f1.z) | (f2bf(f1.w) << 16);
  out[i] = o;
}

// ============ 128x256 GEMM (fp32-A reg-staged) + fused local scan =========
// EXACT R15 structure (last passing) with ONE change: ASTORE uses
// v_cvt_pk_bf16_f32 (4 instrs) instead of 4x f2bf bit-ops (~36 instrs) in
// the serial between-drain window. R16's schedule reorder is REVERTED
// (suspected register-liveness hazard on in-flight asm load outputs).
// h = scan(z), z = x @ W^T. x fp32 read direct; Wb bf16.
// BM=128, BN=256, BK=32, 8 waves (2Mx4N), triple-buffered LDS slots.
// Wait schedule (R15-proven): iter kt: [B(kt+2) DMA] -> frag reads ->
//   vmcnt(2) -> cvt+write A(kt+2) -> load A(kt+3) -> lgkmcnt(0) -> BAR
//   -> 16 MFMA.  Tail: vmcnt(0) last two iters (R11 epilogue safety).

#define BAR() __builtin_amdgcn_s_barrier()
#define SB0() __builtin_amdgcn_sched_barrier(0)
#define HSTRIDE 260

__global__ __launch_bounds__(512, 4) void gemm_scan(const float* __restrict__ X,
                                                    const ushort_t* __restrict__ Bm,
                                                    ushort_t* __restrict__ Hout,
                                                    float* __restrict__ mfin,
                                                    const float* __restrict__ lam_logit,
                                                    const float* __restrict__ eta) {
  const int N = 2048;
  const int NT = 64;  // K / 32
  __shared__ alignas(16) char smem[73728];  // 3x8KB A + 3x16KB B slots

  // tm-chunked XCD swizzle over 512 blocks: XCD x -> tm in [8x, 8x+8), all tn
  int bid = blockIdx.x;
  int tm = (bid & 7) * 8 + ((bid >> 3) & 7);   // 64 row tiles
  int tn = bid >> 6;                            // 8 col tiles
  int rowBase = tm * 128;
  int colBase = tn * 256;

  int tid  = threadIdx.x;
  int lane = tid & 63;
  int wid  = tid >> 6;
  int wm = wid >> 2;           // 0..1
  int wn = wid & 3;            // 0..3
  int fr  = lane & 15;
  int c16 = lane >> 4;

  // ---- A reg-stage addressing: thread covers (arow, akg) of the 128x32 tile
  int arow = tid >> 2;         // 0..127
  int akg  = tid & 3;          // 0..3  (8 fp32 each)
  const float* xA = X + (size_t)(rowBase + arow) * DDIM + akg * 8;
  int abyte = (arow * 64 + akg * 16) ^ (((arow >> 1) & 3) << 4);  // swizzled

  // ---- B DMA source (inverse-swizzled), two 8KB halves
  const char* pB0;
  const char* pB1;
  {
    int o = tid * 16;
    int lb = o ^ (((o >> 7) & 3) << 4);
    pB0 = (const char*)Bm + ((size_t)(colBase + (lb >> 6)) * DDIM) * 2 + (lb & 63);
    int o1 = 8192 + tid * 16;
    int lb1 = o1 ^ (((o1 >> 7) & 3) << 4);
    pB1 = (const char*)Bm + ((size_t)(colBase + (lb1 >> 6)) * DDIM) * 2 + (lb1 & 63);
  }

  // swizzled LDS byte offsets for fragment reads
  int lbA_[4], lbB_[4];
#pragma unroll
  for (int m = 0; m < 4; ++m) {
    int row = wm * 64 + m * 16 + fr;
    lbA_[m] = (row * 64 + c16 * 16) ^ (((row >> 1) & 3) << 4);
  }
#pragma unroll
  for (int n = 0; n < 4; ++n) {
    int row = wn * 64 + n * 16 + fr;
    lbB_[n] = (row * 64 + c16 * 16) ^ (((row >> 1) & 3) << 4);
  }

  f32x4 acc[4][4];
#pragma unroll
  for (int m = 0; m < 4; ++m)
#pragma unroll
    for (int n = 0; n < 4; ++n) acc[m][n] = (f32x4){0.f, 0.f, 0.f, 0.f};

#define DMAB(slotB, koff)                                                     \
  {                                                                           \
    char* db = (char*)(slotB) + tid * 16;                                     \
    __builtin_amdgcn_global_load_lds(                                         \
        (const __attribute__((address_space(1))) void*)(pB0 + (koff)),       \
        (__attribute__((address_space(3))) void*)db, 16, 0, 0);               \
    __builtin_amdgcn_global_load_lds(                                         \
        (const __attribute__((address_space(1))) void*)(pB1 + (koff)),       \
        (__attribute__((address_space(3))) void*)(db + 8192), 16, 0, 0);      \
  }

  f32x4 ar_lo, ar_hi;
#define ALOAD(kt3)                                                            \
  {                                                                           \
    const float* ap = xA + (size_t)(kt3) * 32;                                \
    SB0();                                                                    \
    asm volatile("global_load_dwordx4 %0, %2, off\n\t"                        \
                 "global_load_dwordx4 %1, %2, off offset:16"                  \
                 : "=&v"(ar_lo), "=&v"(ar_hi) : "v"(ap));                     \
    SB0();                                                                    \
  }

#define ASTORE(slotA)                                                         \
  {                                                                           \
    uint_t w0, w1, w2, w3;                                                    \
    asm("v_cvt_pk_bf16_f32 %0, %1, %2" : "=v"(w0)                            \
        : "v"(ar_lo[0]), "v"(ar_lo[1]));                                      \
    asm("v_cvt_pk_bf16_f32 %0, %1, %2" : "=v"(w1)                            \
        : "v"(ar_lo[2]), "v"(ar_lo[3]));                                      \
    asm("v_cvt_pk_bf16_f32 %0, %1, %2" : "=v"(w2)                            \
        : "v"(ar_hi[0]), "v"(ar_hi[1]));                                      \
    asm("v_cvt_pk_bf16_f32 %0, %1, %2" : "=v"(w3)                            \
        : "v"(ar_hi[2]), "v"(ar_hi[3]));                                      \
    uint4 v = {w0, w1, w2, w3};                                               \
    *(uint4*)((char*)(slotA) + abyte) = v;                                    \
  }

  char* qa0 = smem;
  char* qa1 = smem + 8192;
  char* qa2 = smem + 16384;
  char* qb0 = smem + 24576;
  char* qb1 = smem + 24576 + 16384;
  char* qb2 = smem + 24576 + 32768;

  // ---- prologue: A0,A1 via regs; B0,B1 DMA; A2 in flight  (R15 exact)
  ALOAD(0);
  SB0(); asm volatile("s_waitcnt vmcnt(0)"); SB0();
  ASTORE(qa0);
  ALOAD(1);
  SB0(); asm volatile("s_waitcnt vmcnt(0)"); SB0();
  ASTORE(qa1);
  DMAB(qb0, 0);
  DMAB(qb1, 64);
  ALOAD(2);
  SB0(); asm volatile("s_waitcnt vmcnt(2)"); SB0();   // drain B0,B1; A2 flying
  SB0(); asm volatile("s_waitcnt lgkmcnt(0)"); SB0(); // A0/A1 stores landed
  BAR();

  short8 a[4], b[4];

#pragma unroll 1
  for (int kt = 0; kt < NT; ++kt) {
    bool mid = (kt + 2 < NT);
    // 1. B DMA for kt+2 -> spare B slot
    if (mid) DMAB(qb2, (kt + 2) * 64);
    // 2. fragment reads for kt
    a[0] = *(const short8*)(qa0 + lbA_[0]);
    a[1] = *(const short8*)(qa0 + lbA_[1]);
    a[2] = *(const short8*)(qa0 + lbA_[2]);
    a[3] = *(const short8*)(qa0 + lbA_[3]);
    b[0] = *(const short8*)(qb0 + lbB_[0]);
    b[1] = *(const short8*)(qb0 + lbB_[1]);
    b[2] = *(const short8*)(qb0 + lbB_[2]);
    b[3] = *(const short8*)(qb0 + lbB_[3]);
    // 3. drain everything except the just-issued B(kt+2): B(kt+1) + A(kt+2) regs
    if (mid) {
      SB0(); asm volatile("s_waitcnt vmcnt(2)"); SB0();
    } else {
      SB0(); asm volatile("s_waitcnt vmcnt(0)"); SB0();
    }
    // 4. convert + write A(kt+2) -> spare A slot
    if (mid) ASTORE(qa2);
    // 5. issue A(kt+3) loads
    if (kt + 3 < NT) ALOAD(kt + 3);
    // 6. all LDS ops (frag reads + A store) done before barrier
    SB0(); asm volatile("s_waitcnt lgkmcnt(0)"); SB0();
    BAR();
    // 7. MFMA cluster
    __builtin_amdgcn_s_setprio(1);
#pragma unroll
    for (int n = 0; n < 4; ++n)
#pragma unroll
      for (int m = 0; m < 4; ++m)
        acc[m][n] = __builtin_amdgcn_mfma_f32_16x16x32_bf16(a[m], b[n], acc[m][n], 0, 0, 0);
    __builtin_amdgcn_s_setprio(0);
    // rotate slots
    char* t0 = qa0; qa0 = qa1; qa1 = qa2; qa2 = t0;
    char* t1 = qb0; qb0 = qb1; qb1 = qb2; qb2 = t1;
  }
  // tail iters used vmcnt(0) and issued nothing new -> no in-flight DMA/loads;
  // last BAR was after all frag reads -> smem reusable by epilogue.

  // ---- epilogue part 1: acc -> LDS bf16 tile [128][HSTRIDE]
  ushort_t* hl = (ushort_t*)smem;
  int crow0 = (lane >> 4) * 4;
  int ccol  = lane & 15;
#pragma unroll
  for (int mi = 0; mi < 4; ++mi)
#pragma unroll
    for (int n = 0; n < 4; ++n)
#pragma unroll
      for (int r = 0; r < 4; ++r) {
        int row = wm * 64 + mi * 16 + crow0 + r;
        int col = wn * 64 + n * 16 + ccol;
        hl[row * HSTRIDE + col] = (ushort_t)f2bf(acc[mi][n][r]);
      }
  BAR();

  // ---- epilogue part 2: per-(col,chunk) gated scan over t (TC=32)
  float lam[KLAM], et[KLAM];
#pragma unroll
  for (int k = 0; k < KLAM; ++k) {
    lam[k] = 1.f / (1.f + __expf(-lam_logit[k]));
    et[k] = eta[k];
  }
  int bidx = rowBase >> 11;   // batch (tiles never cross b)
#pragma unroll
  for (int it = 0; it < 2; ++it) {
    int task = tid + it * 512;        // 1024 tasks: (chunk 0..3) x (col 0..255)
    int col = task & 255;
    int r0 = (task >> 8) * 32;
    float m[KLAM] = {0.f, 0.f, 0.f, 0.f};
#pragma unroll 4
    for (int t = 0; t < TC; ++t) {
      float zv = bf2f(hl[(r0 + t) * HSTRIDE + col]);
      float h = zv;
#pragma unroll
      for (int k = 0; k < KLAM; ++k) {
        m[k] = fmaf(lam[k], m[k], zv);
        h = fmaf(et[k], m[k], h);
      }
      hl[(r0 + t) * HSTRIDE + col] = (ushort_t)f2bf(h);
    }
    int cglob = ((rowBase + r0) & (TDIM - 1)) >> 5;
    int dglob = colBase + col;
#pragma unroll
    for (int k = 0; k < KLAM; ++k)
      mfin[(((size_t)(bidx * CCH + cglob)) * KLAM + k) * DDIM + dglob] = m[k];
  }
  BAR();

  // ---- epilogue part 3: coalesced h store (128 rows x 256 cols bf16)
#pragma unroll
  for (int i8 = 0; i8 < 8; ++i8) {
    int i = tid + i8 * 512;           // 4096 x uint4
    int row = i >> 5;
    int c8 = (i & 31) * 8;
    uint2 lo = *(const uint2*)&hl[row * HSTRIDE + c8];
    uint2 hi = *(const uint2*)&hl[row * HSTRIDE + c8 + 4];
    uint4 v = {lo.x, lo.y, hi.x, hi.y};
    *(uint4*)&Hout[(size_t)(rowBase + row) * N + colBase + c8] = v;
  }
}

// ---------------- carry prefix across chunks ----------------
__global__ __launch_bounds__(256) void scan_carry(const float* __restrict__ mfin,
                                                  float* __restrict__ carry,
                                                  const float* __restrict__ lam_logit) {
  int idx = blockIdx.x * 256 + threadIdx.x;
  int d = idx & (DDIM - 1);
  int k = (idx >> 11) & 3;
  int b = idx >> 13;
  float lam = 1.f / (1.f + __expf(-lam_logit[k]));
  // lam^TC (TC=32) by repeated squaring
  float lamTc = lam;
  lamTc *= lamTc; lamTc *= lamTc; lamTc *= lamTc;
  lamTc *= lamTc; lamTc *= lamTc;
  float run = 0.f;
  carry[(((size_t)(b * CCH + 0)) * KLAM + k) * DDIM + d] = 0.f;
  for (int c = 1; c < CCH; ++c) {
    run = fmaf(lamTc, run, mfin[(((size_t)(b * CCH + c - 1)) * KLAM + k) * DDIM + d]);
    carry[(((size_t)(b * CCH + c)) * KLAM + k) * DDIM + d] = run;
  }
}

// ---------------- carry correction + LayerNorm (block per (b,t)) ----------------
// XCD-contiguous bt swizzle: each XCD covers a contiguous 1024-row range, so
// each chunk's 32KB carry slice stays L2-resident per XCD.
__global__ __launch_bounds__(256) void ln_fuse(const ushort_t* __restrict__ hpart,
                                               const float* __restrict__ carry,
                                               const float* __restrict__ lam_logit,
                                               const float* __restrict__ eta,
                                               const float* __restrict__ gamma,
                                               const float* __restrict__ beta,
                                               float* __restrict__ out) {
  int bid = blockIdx.x;
  int bt = (bid & 7) * ((BDIM * TDIM) / 8) + (bid >> 3);  // bijective over 8192
  int t = bt & (TDIM - 1);
  int b = bt >> 11;
  int c = t >> 5;                 // chunk (TC=32)
  int dt = (t & (TC - 1)) + 1;

  float sc[KLAM];
#pragma unroll
  for (int k = 0; k < KLAM; ++k) {
    float lam = 1.f / (1.f + __expf(-lam_logit[k]));
    sc[k] = eta[k] * powf(lam, (float)dt);
  }

  int d0 = threadIdx.x * 8;
  size_t rowoff = (size_t)bt * DDIM;

  float h[8];
  {
    uint4 hv = *(const uint4*)&hpart[rowoff + d0];
    h[0] = bf2f(hv.x & 0xffffu); h[1] = bf2f(hv.x >> 16);
    h[2] = bf2f(hv.y & 0xffffu); h[3] = bf2f(hv.y >> 16);
    h[4] = bf2f(hv.z & 0xffffu); h[5] = bf2f(hv.z >> 16);
    h[6] = bf2f(hv.w & 0xffffu); h[7] = bf2f(hv.w >> 16);
  }
  size_t cb = ((size_t)(b * CCH + c)) * KLAM * DDIM + d0;
#pragma unroll
  for (int k = 0; k < KLAM; ++k) {
    float4 c0 = *(const float4*)&carry[cb + (size_t)k * DDIM];
    float4 c1 = *(const float4*)&carry[cb + (size_t)k * DDIM + 4];
    h[0] = fmaf(sc[k], c0.x, h[0]);
    h[1] = fmaf(sc[k], c0.y, h[1]);
    h[2] = fmaf(sc[k], c0.z, h[2]);
    h[3] = fmaf(sc[k], c0.w, h[3]);
    h[4] = fmaf(sc[k], c1.x, h[4]);
    h[5] = fmaf(sc[k], c1.y, h[5]);
    h[6] = fmaf(sc[k], c1.z, h[6]);
    h[7] = fmaf(sc[k], c1.w, h[7]);
  }

  float s = 0.f, ss = 0.f;
#pragma unroll
  for (int j = 0; j < 8; ++j) { s += h[j]; ss += h[j] * h[j]; }
#pragma unroll
  for (int off = 32; off > 0; off >>= 1) {
    s  += __shfl_xor(s, off, 64);
    ss += __shfl_xor(ss, off, 64);
  }
  __shared__ float red[8];
  int wv = threadIdx.x >> 6;
  if ((threadIdx.x & 63) == 0) { red[wv] = s; red[4 + wv] = ss; }
  __syncthreads();
  float st  = red[0] + red[1] + red[2] + red[3];
  float sst = red[4] + red[5] + red[6] + red[7];

  const float invD = 1.f / (float)DDIM;
  float mu = st * invD;
  float var = sst * invD - mu * mu;
  float inv = rsqrtf(var + 1e-5f);

  float4 g0 = *(const float4*)&gamma[d0];
  float4 g1 = *(const float4*)&gamma[d0 + 4];
  float4 b0 = *(const float4*)&beta[d0];
  float4 b1 = *(const float4*)&beta[d0 + 4];
  float4 o0, o1;
  o0.x = g0.x * (h[0] - mu) * inv + b0.x;
  o0.y = g0.y * (h[1] - mu) * inv + b0.y;
  o0.z = g0.z * (h[2] - mu) * inv + b0.z;
  o0.w = g0.w * (h[3] - mu) * inv + b0.w;
  o1.x = g1.x * (h[4] - mu) * inv + b1.x;
  o1.y = g1.y * (h[5] - mu) * inv + b1.y;
  o1.z = g1.z * (h[6] - mu) * inv + b1.z;
  o1.w = g1.w * (h[7] - mu) * inv + b1.w;
  *(float4*)&out[rowoff + d0] = o0;
  *(float4*)&out[rowoff + d0 + 4] = o1;
}

extern "C" void kernel_launch(void* const* d_in, const int* in_sizes, int n_in,
                              void* d_out, int out_size, void* d_ws, size_t ws_size,
                              hipStream_t stream) {
  const float* x         = (const float*)d_in[0];
  const float* W         = (const float*)d_in[1];
  const float* lam_logit = (const float*)d_in[2];
  const float* eta       = (const float*)d_in[3];
  const float* gamma     = (const float*)d_in[4];
  const float* beta      = (const float*)d_in[5];
  float* out = (float*)d_out;

  char* ws = (char*)d_ws;
  // layout: [Wb 8MB][hb 32MB][mfin 8MB][carry 8MB] = 56MB
  ushort_t* Wb = (ushort_t*)ws;
  ushort_t* hb = (ushort_t*)(ws + (size_t)8388608);
  float*    mfin  = (float*)(ws + (size_t)8388608 + 33554432);
  float*    carry = (float*)(ws + (size_t)8388608 + 33554432 + 8388608);

  cvt_w<<<NW8 / 256, 256, 0, stream>>>(W, (uint4*)Wb);

  gemm_scan<<<512, 512, 0, stream>>>(x, Wb, hb, mfin, lam_logit, eta);

  scan_carry<<<(BDIM * KLAM * DDIM) / 256, 256, 0, stream>>>(mfin, carry, lam_logit);
  ln_fuse<<<BDIM * TDIM, 256, 0, stream>>>(hb, carry, lam_logit, eta, gamma, beta, out);
}

// Round 19
// 137.411 us; speedup vs baseline: 1.0041x; 1.0041x over previous
//
#include <hip/hip_runtime.h>

// Problem dims
#define BDIM 4
#define TDIM 2048
#define DDIM 2048
#define KLAM 4
#define CCH  64          // time chunks
#define TC   32          // TDIM / CCH

using short8 = __attribute__((ext_vector_type(8))) short;
using f32x4  = __attribute__((ext_vector_type(4))) float;
typedef unsigned short ushort_t;
typedef unsigned int   uint_t;

__device__ __forceinline__ uint_t f2bf(float f) {
  uint_t u = __builtin_bit_cast(uint_t, f);
  return (u + 0x7FFFu + ((u >> 16) & 1u)) >> 16;
}
__device__ __forceinline__ float bf2f(uint_t s) {
  uint_t u = s << 16;
  return __builtin_bit_cast(float, u);
}

#define NW8 ((DDIM * DDIM) / 8)          // 524288

// ---------------- fp32 -> bf16 convert (W only; x is read fp32 by gemm) ----
__global__ __launch_bounds__(256) void cvt_w(const float* __restrict__ in,
                                             uint4* __restrict__ out) {
  int i = blockIdx.x * 256 + threadIdx.x;
  const float4* in4 = (const float4*)in;
  float4 f0 = in4[2 * i];
  float4 f1 = in4[2 * i + 1];
  uint4 o;
  o.x = f2bf(f0.x) | (f2bf(f0.y) << 16);
  o.y = f2bf(f0.z) | (f2bf(f0.w) << 16);
  o.z = f2bf(f1.x) | (f2bf(f1.y) << 16);
  o.w = f2bf(f1.z) | (f2bf(f1.w) << 16);
  out[i] = o;
}

// ============ 128x256 GEMM (fp32-A reg-staged) + fused local scan =========
// R18 base (passing, 95 us) with the A-window MOVED INTO THE MFMA SHADOW:
//   iter kt: [DMAB B(kt+2)] [frag reads kt] [vmcnt(4): drain B(kt+1) only]
//            [lgkmcnt(0)] [BAR] [16 MFMA] [vmcnt(2): drain A(kt+2) regs]
//            [ASTORE A(kt+2)] [ALOAD(kt+3)]
// cvt_pk/ds_write/load-issue run on VALU/LDS/VMEM pipes while the matrix
// pipe drains -> off the serial path. A(kt+2)'s ds_write is covered by
// iter kt+1's lgkmcnt(0)+BAR, two barriers before its readers (iter kt+2).
// Queue (steady): pre-BAR = B(kt+1),A(kt+2),B(kt+2) -> vmcnt(4);
// post-MFMA = A(kt+2),B(kt+2) -> vmcnt(2). Tails: pre-BAR vmcnt(0) for
// kt>=NT-2; loop exits with empty queue (R11 epilogue-reuse safety).
// Epilogue: acc -> LDS bf16 [128][260]; part2 scan u32-vectorized
// (2 cols/thread, single pass); coalesced h store + mfin.

#define BAR() __builtin_amdgcn_s_barrier()
#define SB0() __builtin_amdgcn_sched_barrier(0)
#define HSTRIDE 260

__global__ __launch_bounds__(512, 4) void gemm_scan(const float* __restrict__ X,
                                                    const ushort_t* __restrict__ Bm,
                                                    ushort_t* __restrict__ Hout,
                                                    float* __restrict__ mfin,
                                                    const float* __restrict__ lam_logit,
                                                    const float* __restrict__ eta) {
  const int N = 2048;
  const int NT = 64;  // K / 32
  __shared__ alignas(16) char smem[73728];  // 3x8KB A + 3x16KB B slots

  // tm-chunked XCD swizzle over 512 blocks: XCD x -> tm in [8x, 8x+8), all tn
  int bid = blockIdx.x;
  int tm = (bid & 7) * 8 + ((bid >> 3) & 7);   // 64 row tiles
  int tn = bid >> 6;                            // 8 col tiles
  int rowBase = tm * 128;
  int colBase = tn * 256;

  int tid  = threadIdx.x;
  int lane = tid & 63;
  int wid  = tid >> 6;
  int wm = wid >> 2;           // 0..1
  int wn = wid & 3;            // 0..3
  int fr  = lane & 15;
  int c16 = lane >> 4;

  // ---- A reg-stage addressing: thread covers (arow, akg) of the 128x32 tile
  int arow = tid >> 2;         // 0..127
  int akg  = tid & 3;          // 0..3  (8 fp32 each)
  const float* xA = X + (size_t)(rowBase + arow) * DDIM + akg * 8;
  int abyte = (arow * 64 + akg * 16) ^ (((arow >> 1) & 3) << 4);  // swizzled

  // ---- B DMA source (inverse-swizzled), two 8KB halves
  const char* pB0;
  const char* pB1;
  {
    int o = tid * 16;
    int lb = o ^ (((o >> 7) & 3) << 4);
    pB0 = (const char*)Bm + ((size_t)(colBase + (lb >> 6)) * DDIM) * 2 + (lb & 63);
    int o1 = 8192 + tid * 16;
    int lb1 = o1 ^ (((o1 >> 7) & 3) << 4);
    pB1 = (const char*)Bm + ((size_t)(colBase + (lb1 >> 6)) * DDIM) * 2 + (lb1 & 63);
  }

  // swizzled LDS byte offsets for fragment reads
  int lbA_[4], lbB_[4];
#pragma unroll
  for (int m = 0; m < 4; ++m) {
    int row = wm * 64 + m * 16 + fr;
    lbA_[m] = (row * 64 + c16 * 16) ^ (((row >> 1) & 3) << 4);
  }
#pragma unroll
  for (int n = 0; n < 4; ++n) {
    int row = wn * 64 + n * 16 + fr;
    lbB_[n] = (row * 64 + c16 * 16) ^ (((row >> 1) & 3) << 4);
  }

  f32x4 acc[4][4];
#pragma unroll
  for (int m = 0; m < 4; ++m)
#pragma unroll
    for (int n = 0; n < 4; ++n) acc[m][n] = (f32x4){0.f, 0.f, 0.f, 0.f};

#define DMAB(slotB, koff)                                                     \
  {                                                                           \
    char* db = (char*)(slotB) + tid * 16;                                     \
    __builtin_amdgcn_global_load_lds(                                         \
        (const __attribute__((address_space(1))) void*)(pB0 + (koff)),       \
        (__attribute__((address_space(3))) void*)db, 16, 0, 0);               \
    __builtin_amdgcn_global_load_lds(                                         \
        (const __attribute__((address_space(1))) void*)(pB1 + (koff)),       \
        (__attribute__((address_space(3))) void*)(db + 8192), 16, 0, 0);      \
  }

  f32x4 ar_lo, ar_hi;
#define ALOAD(kt3)                                                            \
  {                                                                           \
    const float* ap = xA + (size_t)(kt3) * 32;                                \
    SB0();                                                                    \
    asm volatile("global_load_dwordx4 %0, %2, off\n\t"                        \
                 "global_load_dwordx4 %1, %2, off offset:16"                  \
                 : "=&v"(ar_lo), "=&v"(ar_hi) : "v"(ap));                     \
    SB0();                                                                    \
  }

#define ASTORE(slotA)                                                         \
  {                                                                           \
    uint_t w0, w1, w2, w3;                                                    \
    asm("v_cvt_pk_bf16_f32 %0, %1, %2" : "=v"(w0)                            \
        : "v"(ar_lo[0]), "v"(ar_lo[1]));                                      \
    asm("v_cvt_pk_bf16_f32 %0, %1, %2" : "=v"(w1)                            \
        : "v"(ar_lo[2]), "v"(ar_lo[3]));                                      \
    asm("v_cvt_pk_bf16_f32 %0, %1, %2" : "=v"(w2)                            \
        : "v"(ar_hi[0]), "v"(ar_hi[1]));                                      \
    asm("v_cvt_pk_bf16_f32 %0, %1, %2" : "=v"(w3)                            \
        : "v"(ar_hi[2]), "v"(ar_hi[3]));                                      \
    uint4 v = {w0, w1, w2, w3};                                               \
    *(uint4*)((char*)(slotA) + abyte) = v;                                    \
  }

  char* qa0 = smem;
  char* qa1 = smem + 8192;
  char* qa2 = smem + 16384;
  char* qb0 = smem + 24576;
  char* qb1 = smem + 24576 + 16384;
  char* qb2 = smem + 24576 + 32768;

  // ---- prologue: A0,A1 stored; B0,B1 DMA; A2 in flight. Queue: B0,B1,A2.
  ALOAD(0);
  SB0(); asm volatile("s_waitcnt vmcnt(0)"); SB0();
  ASTORE(qa0);
  ALOAD(1);
  SB0(); asm volatile("s_waitcnt vmcnt(0)"); SB0();
  ASTORE(qa1);
  DMAB(qb0, 0);
  DMAB(qb1, 64);
  ALOAD(2);
  SB0(); asm volatile("s_waitcnt vmcnt(4)"); SB0();   // drain B0; B1+A2 fly
  SB0(); asm volatile("s_waitcnt lgkmcnt(0)"); SB0(); // A0/A1 stores landed
  BAR();

  short8 a[4], b[4];

#pragma unroll 1
  for (int kt = 0; kt < NT; ++kt) {
    // 1. B DMA for kt+2 -> spare B slot
    if (kt + 2 < NT) DMAB(qb2, (kt + 2) * 64);
    // 2. fragment reads for kt
    a[0] = *(const short8*)(qa0 + lbA_[0]);
    a[1] = *(const short8*)(qa0 + lbA_[1]);
    a[2] = *(const short8*)(qa0 + lbA_[2]);
    a[3] = *(const short8*)(qa0 + lbA_[3]);
    b[0] = *(const short8*)(qb0 + lbB_[0]);
    b[1] = *(const short8*)(qb0 + lbB_[1]);
    b[2] = *(const short8*)(qb0 + lbB_[2]);
    b[3] = *(const short8*)(qb0 + lbB_[3]);
    // 3. pre-BAR: drain exactly B(kt+1); A(kt+2) stays in flight.
    //    Queue here: B(kt+1)[2], A(kt+2)[2], B(kt+2)[2].
    if (kt < NT - 2) {
      SB0(); asm volatile("s_waitcnt vmcnt(4)"); SB0();
    } else {
      SB0(); asm volatile("s_waitcnt vmcnt(0)"); SB0();
    }
    // 4. frag reads (and prev iter's ASTORE ds_write) complete before BAR
    SB0(); asm volatile("s_waitcnt lgkmcnt(0)"); SB0();
    BAR();
    // 5. MFMA cluster
    __builtin_amdgcn_s_setprio(1);
#pragma unroll
    for (int n = 0; n < 4; ++n)
#pragma unroll
      for (int m = 0; m < 4; ++m)
        acc[m][n] = __builtin_amdgcn_mfma_f32_16x16x32_bf16(a[m], b[n], acc[m][n], 0, 0, 0);
    __builtin_amdgcn_s_setprio(0);
    // 6. A-window in the MFMA drain shadow: drain A(kt+2) regs, store, reload
    if (kt + 2 < NT) {
      SB0(); asm volatile("s_waitcnt vmcnt(2)"); SB0();
      ASTORE(qa2);
    }
    if (kt + 3 < NT) ALOAD(kt + 3);
    // rotate slots
    char* t0 = qa0; qa0 = qa1; qa1 = qa2; qa2 = t0;
    char* t1 = qb0; qb0 = qb1; qb1 = qb2; qb2 = t1;
  }
  // queue empty at exit (tail vmcnt(0) iters); all frag reads completed
  // before the final BAR -> smem reusable by epilogue.

  // ---- epilogue part 1: acc -> LDS bf16 tile [128][HSTRIDE]
  ushort_t* hl = (ushort_t*)smem;
  int crow0 = (lane >> 4) * 4;
  int ccol  = lane & 15;
#pragma unroll
  for (int mi = 0; mi < 4; ++mi)
#pragma unroll
    for (int n = 0; n < 4; ++n)
#pragma unroll
      for (int r = 0; r < 4; ++r) {
        int row = wm * 64 + mi * 16 + crow0 + r;
        int col = wn * 64 + n * 16 + ccol;
        hl[row * HSTRIDE + col] = (ushort_t)f2bf(acc[mi][n][r]);
      }
  BAR();

  // ---- epilogue part 2: gated scan over t (TC=32), u32-vectorized:
  // 512 tasks = (chunk 0..3) x (colpair 0..127), 2 adjacent cols per thread
  float lam[KLAM], et[KLAM];
#pragma unroll
  for (int k = 0; k < KLAM; ++k) {
    lam[k] = 1.f / (1.f + __expf(-lam_logit[k]));
    et[k] = eta[k];
  }
  int bidx = rowBase >> 11;   // batch (tiles never cross b)
  {
    int cp = tid & 127;              // col pair -> cols 2cp, 2cp+1
    int r0 = (tid >> 7) * 32;        // chunk row base
    float m0[KLAM] = {0.f, 0.f, 0.f, 0.f};
    float m1[KLAM] = {0.f, 0.f, 0.f, 0.f};
#pragma unroll 4
    for (int t = 0; t < TC; ++t) {
      uint_t v = *(const uint_t*)&hl[(r0 + t) * HSTRIDE + 2 * cp];
      float z0 = bf2f(v & 0xffffu);
      float z1 = bf2f(v >> 16);
      float h0 = z0, h1 = z1;
#pragma unroll
      for (int k = 0; k < KLAM; ++k) {
        m0[k] = fmaf(lam[k], m0[k], z0);
        m1[k] = fmaf(lam[k], m1[k], z1);
        h0 = fmaf(et[k], m0[k], h0);
        h1 = fmaf(et[k], m1[k], h1);
      }
      *(uint_t*)&hl[(r0 + t) * HSTRIDE + 2 * cp] = f2bf(h0) | (f2bf(h1) << 16);
    }
    int cglob = ((rowBase + r0) & (TDIM - 1)) >> 5;
    int dglob = colBase + 2 * cp;
#pragma unroll
    for (int k = 0; k < KLAM; ++k) {
      float2 mm = {m0[k], m1[k]};
      *(float2*)&mfin[(((size_t)(bidx * CCH + cglob)) * KLAM + k) * DDIM + dglob] = mm;
    }
  }
  BAR();

  // ---- epilogue part 3: coalesced h store (128 rows x 256 cols bf16)
#pragma unroll
  for (int i8 = 0; i8 < 8; ++i8) {
    int i = tid + i8 * 512;           // 4096 x uint4
    int row = i >> 5;
    int c8 = (i & 31) * 8;
    uint2 lo = *(const uint2*)&hl[row * HSTRIDE + c8];
    uint2 hi = *(const uint2*)&hl[row * HSTRIDE + c8 + 4];
    uint4 v = {lo.x, lo.y, hi.x, hi.y};
    *(uint4*)&Hout[(size_t)(rowBase + row) * N + colBase + c8] = v;
  }
}

// ---------------- carry prefix across chunks ----------------
__global__ __launch_bounds__(256) void scan_carry(const float* __restrict__ mfin,
                                                  float* __restrict__ carry,
                                                  const float* __restrict__ lam_logit) {
  int idx = blockIdx.x * 256 + threadIdx.x;
  int d = idx & (DDIM - 1);
  int k = (idx >> 11) & 3;
  int b = idx >> 13;
  float lam = 1.f / (1.f + __expf(-lam_logit[k]));
  // lam^TC (TC=32) by repeated squaring
  float lamTc = lam;
  lamTc *= lamTc; lamTc *= lamTc; lamTc *= lamTc;
  lamTc *= lamTc; lamTc *= lamTc;
  float run = 0.f;
  carry[(((size_t)(b * CCH + 0)) * KLAM + k) * DDIM + d] = 0.f;
  for (int c = 1; c < CCH; ++c) {
    run = fmaf(lamTc, run, mfin[(((size_t)(b * CCH + c - 1)) * KLAM + k) * DDIM + d]);
    carry[(((size_t)(b * CCH + c)) * KLAM + k) * DDIM + d] = run;
  }
}

// ---------------- carry correction + LayerNorm (block per (b,t)) ----------------
// XCD-contiguous bt swizzle: each XCD covers a contiguous 1024-row range, so
// each chunk's 32KB carry slice stays L2-resident per XCD.
__global__ __launch_bounds__(256) void ln_fuse(const ushort_t* __restrict__ hpart,
                                               const float* __restrict__ carry,
                                               const float* __restrict__ lam_logit,
                                               const float* __restrict__ eta,
                                               const float* __restrict__ gamma,
                                               const float* __restrict__ beta,
                                               float* __restrict__ out) {
  int bid = blockIdx.x;
  int bt = (bid & 7) * ((BDIM * TDIM) / 8) + (bid >> 3);  // bijective over 8192
  int t = bt & (TDIM - 1);
  int b = bt >> 11;
  int c = t >> 5;                 // chunk (TC=32)
  int dt = (t & (TC - 1)) + 1;

  float sc[KLAM];
#pragma unroll
  for (int k = 0; k < KLAM; ++k) {
    float lam = 1.f / (1.f + __expf(-lam_logit[k]));
    sc[k] = eta[k] * powf(lam, (float)dt);
  }

  int d0 = threadIdx.x * 8;
  size_t rowoff = (size_t)bt * DDIM;

  float h[8];
  {
    uint4 hv = *(const uint4*)&hpart[rowoff + d0];
    h[0] = bf2f(hv.x & 0xffffu); h[1] = bf2f(hv.x >> 16);
    h[2] = bf2f(hv.y & 0xffffu); h[3] = bf2f(hv.y >> 16);
    h[4] = bf2f(hv.z & 0xffffu); h[5] = bf2f(hv.z >> 16);
    h[6] = bf2f(hv.w & 0xffffu); h[7] = bf2f(hv.w >> 16);
  }
  size_t cb = ((size_t)(b * CCH + c)) * KLAM * DDIM + d0;
#pragma unroll
  for (int k = 0; k < KLAM; ++k) {
    float4 c0 = *(const float4*)&carry[cb + (size_t)k * DDIM];
    float4 c1 = *(const float4*)&carry[cb + (size_t)k * DDIM + 4];
    h[0] = fmaf(sc[k], c0.x, h[0]);
    h[1] = fmaf(sc[k], c0.y, h[1]);
    h[2] = fmaf(sc[k], c0.z, h[2]);
    h[3] = fmaf(sc[k], c0.w, h[3]);
    h[4] = fmaf(sc[k], c1.x, h[4]);
    h[5] = fmaf(sc[k], c1.y, h[5]);
    h[6] = fmaf(sc[k], c1.z, h[6]);
    h[7] = fmaf(sc[k], c1.w, h[7]);
  }

  float s = 0.f, ss = 0.f;
#pragma unroll
  for (int j = 0; j < 8; ++j) { s += h[j]; ss += h[j] * h[j]; }
#pragma unroll
  for (int off = 32; off > 0; off >>= 1) {
    s  += __shfl_xor(s, off, 64);
    ss += __shfl_xor(ss, off, 64);
  }
  __shared__ float red[8];
  int wv = threadIdx.x >> 6;
  if ((threadIdx.x & 63) == 0) { red[wv] = s; red[4 + wv] = ss; }
  __syncthreads();
  float st  = red[0] + red[1] + red[2] + red[3];
  float sst = red[4] + red[5] + red[6] + red[7];

  const float invD = 1.f / (float)DDIM;
  float mu = st * invD;
  float var = sst * invD - mu * mu;
  float inv = rsqrtf(var + 1e-5f);

  float4 g0 = *(const float4*)&gamma[d0];
  float4 g1 = *(const float4*)&gamma[d0 + 4];
  float4 b0 = *(const float4*)&beta[d0];
  float4 b1 = *(const float4*)&beta[d0 + 4];
  float4 o0, o1;
  o0.x = g0.x * (h[0] - mu) * inv + b0.x;
  o0.y = g0.y * (h[1] - mu) * inv + b0.y;
  o0.z = g0.z * (h[2] - mu) * inv + b0.z;
  o0.w = g0.w * (h[3] - mu) * inv + b0.w;
  o1.x = g1.x * (h[4] - mu) * inv + b1.x;
  o1.y = g1.y * (h[5] - mu) * inv + b1.y;
  o1.z = g1.z * (h[6] - mu) * inv + b1.z;
  o1.w = g1.w * (h[7] - mu) * inv + b1.w;
  *(float4*)&out[rowoff + d0] = o0;
  *(float4*)&out[rowoff + d0 + 4] = o1;
}

extern "C" void kernel_launch(void* const* d_in, const int* in_sizes, int n_in,
                              void* d_out, int out_size, void* d_ws, size_t ws_size,
                              hipStream_t stream) {
  const float* x         = (const float*)d_in[0];
  const float* W         = (const float*)d_in[1];
  const float* lam_logit = (const float*)d_in[2];
  const float* eta       = (const float*)d_in[3];
  const float* gamma     = (const float*)d_in[4];
  const float* beta      = (const float*)d_in[5];
  float* out = (float*)d_out;

  char* ws = (char*)d_ws;
  // layout: [Wb 8MB][hb 32MB][mfin 8MB][carry 8MB] = 56MB
  ushort_t* Wb = (ushort_t*)ws;
  ushort_t* hb = (ushort_t*)(ws + (size_t)8388608);
  float*    mfin  = (float*)(ws + (size_t)8388608 + 33554432);
  float*    carry = (float*)(ws + (size_t)8388608 + 33554432 + 8388608);

  cvt_w<<<NW8 / 256, 256, 0, stream>>>(W, (uint4*)Wb);

  gemm_scan<<<512, 512, 0, stream>>>(x, Wb, hb, mfin, lam_logit, eta);

  scan_carry<<<(BDIM * KLAM * DDIM) / 256, 256, 0, stream>>>(mfin, carry, lam_logit);
  ln_fuse<<<BDIM * TDIM, 256, 0, stream>>>(hb, carry, lam_logit, eta, gamma, beta, out);
}